// Round 5
// baseline (1502.318 us; speedup 1.0000x reference)
//
#include <hip/hip_runtime.h>

typedef unsigned int u32;
typedef unsigned long long u64;

// Problem constants
#define T_ 4
#define B_ 16
#define N_ 256
#define C_ 256
#define H_ 8
#define D_ 32
#define BNC_ 1048576   // B*N*C
#define NELEM 4194304  // T*B*N*C

// ---------------------------------------------------------------------------
// Fused multi-W GEMM + eval-BatchNorm.  O[w][m,o] = BN_w(sum_c A[m,c]*W[w][o,c])
// Round-5 theory: GEMM is DS-instruction-bound (one DS pipe/CU, ~12cyc per
// ds_read_b128 even with broadcast). Fusing the 3 QKV GEMMs over shared A
// amortizes A-fragment reads: per wave-kk 5 reads feed 96 FMA-instr
// (ratio 0.31 vs 1.13 unfused) -> ~80% VALU ceiling.
// 128x64 tile, 256 thr, 8x4 micro, A double-buffered LDS (k-major),
// W single-buffered (2 barriers/slab), slab s+1 register-prefetched.
// FMA chain per output strictly k-ascending (bit-exact vs reference).
// ---------------------------------------------------------------------------
template<int NW>
__global__ __launch_bounds__(256, 2) void gemm_bn_f(
    const float* __restrict__ A,
    const float* __restrict__ W0, const float* __restrict__ W1,
    const float* __restrict__ W2,
    const float* __restrict__ bn0, const float* __restrict__ bn1,
    const float* __restrict__ bn2,
    float* __restrict__ O0, float* __restrict__ O1, float* __restrict__ O2)
{
  __shared__ float As[2][32][132];     // [buf][k][row] k-major, 132 pad
  __shared__ float Ws[NW][32][68];     // [w][k][row]   k-major, 68 pad
  const int tid = threadIdx.x;
  const int m0 = blockIdx.y << 7;      // 128 rows
  const int n0 = blockIdx.x << 6;      // 64 cols
  const int tx = tid & 15;             // col group (4 cols)
  const int ty = tid >> 4;             // row group (8 rows)
  const int arow = tid >> 1, ak = (tid & 1) << 4;   // A loader: 1 row, 16 ks
  const int brow = tid >> 2, bk = (tid & 3) << 3;   // W loader: 1 row, 8 ks

  const float* Wp[3] = {W0, W1, W2};
  const float* bnp[3] = {bn0, bn1, bn2};
  float* Op[3] = {O0, O1, O2};

  const float* aP = A + (size_t)(m0 + arow) * 256 + ak;
  const float* wP[3];
#pragma unroll
  for (int w = 0; w < NW; ++w) wP[w] = Wp[w] + (size_t)(n0 + brow) * 256 + bk;

  float acc[NW][8][4] = {};
  float4 pa[4]; float4 pw[NW][2];

  // ---- prologue: load + write slab 0
#pragma unroll
  for (int c = 0; c < 4; ++c) pa[c] = *(const float4*)(aP + (c << 2));
#pragma unroll
  for (int w = 0; w < NW; ++w)
#pragma unroll
    for (int c = 0; c < 2; ++c)
      pw[w][c] = *(const float4*)(wP[w] + (c << 2));
#pragma unroll
  for (int c = 0; c < 4; ++c) {
    As[0][ak + (c<<2) + 0][arow] = pa[c].x;
    As[0][ak + (c<<2) + 1][arow] = pa[c].y;
    As[0][ak + (c<<2) + 2][arow] = pa[c].z;
    As[0][ak + (c<<2) + 3][arow] = pa[c].w;
  }
#pragma unroll
  for (int w = 0; w < NW; ++w)
#pragma unroll
    for (int c = 0; c < 2; ++c) {
      Ws[w][bk + (c<<2) + 0][brow] = pw[w][c].x;
      Ws[w][bk + (c<<2) + 1][brow] = pw[w][c].y;
      Ws[w][bk + (c<<2) + 2][brow] = pw[w][c].z;
      Ws[w][bk + (c<<2) + 3][brow] = pw[w][c].w;
    }
  __syncthreads();

  int cur = 0;
  for (int s = 0; s < 8; ++s) {
    if (s < 7) {                      // prefetch slab s+1 into regs
      const int k0 = (s + 1) << 5;
#pragma unroll
      for (int c = 0; c < 4; ++c) pa[c] = *(const float4*)(aP + k0 + (c << 2));
#pragma unroll
      for (int w = 0; w < NW; ++w)
#pragma unroll
        for (int c = 0; c < 2; ++c)
          pw[w][c] = *(const float4*)(wP[w] + k0 + (c << 2));
    }
#pragma unroll
    for (int kk = 0; kk < 32; ++kk) {
      const float4 a0 = *(const float4*)&As[cur][kk][ty << 3];
      const float4 a1 = *(const float4*)&As[cur][kk][(ty << 3) + 4];
      const float ar[8] = {a0.x, a0.y, a0.z, a0.w, a1.x, a1.y, a1.z, a1.w};
#pragma unroll
      for (int w = 0; w < NW; ++w) {
        const float4 b4 = *(const float4*)&Ws[w][kk][tx << 2];
        const float br[4] = {b4.x, b4.y, b4.z, b4.w};
#pragma unroll
        for (int ii = 0; ii < 8; ++ii)
#pragma unroll
          for (int jj = 0; jj < 4; ++jj)
            acc[w][ii][jj] = fmaf(ar[ii], br[jj], acc[w][ii][jj]);
      }
    }
    if (s < 7) {
      __syncthreads();                // all waves done reading slab s
#pragma unroll
      for (int c = 0; c < 4; ++c) {
        As[cur ^ 1][ak + (c<<2) + 0][arow] = pa[c].x;
        As[cur ^ 1][ak + (c<<2) + 1][arow] = pa[c].y;
        As[cur ^ 1][ak + (c<<2) + 2][arow] = pa[c].z;
        As[cur ^ 1][ak + (c<<2) + 3][arow] = pa[c].w;
      }
#pragma unroll
      for (int w = 0; w < NW; ++w)
#pragma unroll
        for (int c = 0; c < 2; ++c) {
          Ws[w][bk + (c<<2) + 0][brow] = pw[w][c].x;
          Ws[w][bk + (c<<2) + 1][brow] = pw[w][c].y;
          Ws[w][bk + (c<<2) + 2][brow] = pw[w][c].z;
          Ws[w][bk + (c<<2) + 3][brow] = pw[w][c].w;
        }
      __syncthreads();                // slab s+1 visible
      cur ^= 1;
    }
  }

  // ---- BN epilogue (identical op sequence to rounds 1-4, absmax 0.0)
#pragma unroll
  for (int w = 0; w < NW; ++w) {
    const float* gma = bnp[w];
    const float* bta = bnp[w] + 256;
    const float* mea = bnp[w] + 512;
    const float* vra = bnp[w] + 768;
    float sc[4], me[4], be[4];
#pragma unroll
    for (int jj = 0; jj < 4; ++jj) {
      int o = n0 + (tx << 2) + jj;
      sc[jj] = __fmul_rn(gma[o], 1.0f / sqrtf(__fadd_rn(vra[o], 1e-5f)));
      me[jj] = mea[o];
      be[jj] = bta[o];
    }
#pragma unroll
    for (int ii = 0; ii < 8; ++ii) {
      int row = m0 + (ty << 3) + ii;
      float4 y;
      y.x = __fadd_rn(__fmul_rn(__fsub_rn(acc[w][ii][0], me[0]), sc[0]), be[0]);
      y.y = __fadd_rn(__fmul_rn(__fsub_rn(acc[w][ii][1], me[1]), sc[1]), be[1]);
      y.z = __fadd_rn(__fmul_rn(__fsub_rn(acc[w][ii][2], me[2]), sc[2]), be[2]);
      y.w = __fadd_rn(__fmul_rn(__fsub_rn(acc[w][ii][3], me[3]), sc[3]), be[3]);
      *(float4*)(Op[w] + (size_t)row * 256 + n0 + (tx << 2)) = y;
    }
  }
}

// ---------------------------------------------------------------------------
// LIF over T (TAU=2, hard reset) + pack spikes into per-head 32-bit masks.
// ---------------------------------------------------------------------------
__global__ __launch_bounds__(256) void lif_pack3(
    const float* __restrict__ h0, const float* __restrict__ h1,
    const float* __restrict__ h2,
    u32* __restrict__ m0p, u32* __restrict__ m1p, u32* __restrict__ m2p)
{
  const float* h = (blockIdx.y == 0) ? h0 : (blockIdx.y == 1) ? h1 : h2;
  u32* mask      = (blockIdx.y == 0) ? m0p : (blockIdx.y == 1) ? m1p : m2p;
  const int blk = blockIdx.x;          // b*256 + n
  const int b = blk >> 8, n = blk & 255;
  const int c = threadIdx.x;
  const int wave = c >> 6, lane = c & 63;
  const size_t idx = ((size_t)b * 256 + n) * 256 + c;
  float v = 0.0f;
#pragma unroll
  for (int t = 0; t < 4; ++t) {
    float xv = h[idx + (size_t)t * BNC_];
    v = __fadd_rn(v, __fmul_rn(__fsub_rn(xv, v), 0.5f));
    bool s = (v >= 1.0f);
    u64 bal = __ballot(s);
    const int h0i = wave << 1;
    u32* mptr = mask + ((size_t)(t * 16 + b) * 8) * 256 + n;
    if (lane == 0)  mptr[(size_t)h0i * 256]       = (u32)bal;
    if (lane == 32) mptr[(size_t)(h0i + 1) * 256] = (u32)(bal >> 32);
    v = s ? 0.0f : v;
  }
}

// ---------------------------------------------------------------------------
// Fused attention: QK^T (popcount) + rel-bias + exact top-64 + sparse PV.
// (unchanged from round 4: 90 us, VALUBusy 83%)
// ---------------------------------------------------------------------------
__global__ __launch_bounds__(256) void attn_topk_pv(
    const u32* __restrict__ qmask, const u32* __restrict__ kmask,
    const u32* __restrict__ vmask, const float* __restrict__ table,
    float* __restrict__ outPV)
{
  __shared__ __align__(16) float bias[511];
  __shared__ __align__(16) u64 comp[4][2][132];  // [wave][half][entries]

  const int tbh = blockIdx.x;
  const int rg = blockIdx.y;
  const int hh = tbh & 7;
  const int tid = threadIdx.x;

  bias[tid] = table[tid * 8 + hh];
  if (tid < 255) bias[256 + tid] = table[(256 + tid) * 8 + hh];
  __syncthreads();

  const int wave = tid >> 6, lane = tid & 63;
  const int d = lane & 31, half = lane >> 5;

  // row-invariant per-lane K/V mask words (j = lane + 64r)
  u32 kmr[4], vmr[4];
#pragma unroll
  for (int r = 0; r < 4; ++r) {
    kmr[r] = kmask[((size_t)tbh << 8) + lane + (r << 6)];
    vmr[r] = vmask[((size_t)tbh << 8) + lane + (r << 6)];
  }
  const u64 below = (1ull << lane) - 1ull;
  u64* const clo = &comp[wave][0][0];
  u64* const chi = &comp[wave][1][0];

#pragma unroll 1
  for (int it = 0; it < 8; ++it) {
    const int i = (rg << 5) + (it << 2) + wave;
    const u32 qm = qmask[((size_t)tbh << 8) + i];
    float a[4]; u32 u[4];
#pragma unroll
    for (int r = 0; r < 4; ++r) {
      const int j = lane + (r << 6);
      const int m = __popc(qm & kmr[r]);
      float av = __fmul_rn((float)m, 0.0625f);     // * C^-0.5 = 1/16 exact
      av = __fadd_rn(av, bias[j - i + 255]);        // one rounded add == ref
      a[r] = av;
      const u32 bb = __float_as_uint(av);
      u[r] = bb ^ ((u32)((int)bb >> 31) | 0x80000000u);
    }
    // MSB-greedy exact 64th-largest; early exit when keep-set pinned
    u32 t = 0u;
    for (int bit = 31; bit >= 0; --bit) {
      const u32 cand = t | (1u << bit);
      const int cnt = __popcll(__ballot(u[0] >= cand)) +
                      __popcll(__ballot(u[1] >= cand)) +
                      __popcll(__ballot(u[2] >= cand)) +
                      __popcll(__ballot(u[3] >= cand));
      if (cnt >= 64) { t = cand; if (cnt == 64) break; }
    }
    // keep ballots -> compaction positions (j-ascending per half)
    const u64 B0 = __ballot(u[0] >= t), B1 = __ballot(u[1] >= t);
    const u64 B2 = __ballot(u[2] >= t), B3 = __ballot(u[3] >= t);
    const int c0 = __popcll(B0), c1 = __popcll(B1);
    const int c2 = __popcll(B2), c3 = __popcll(B3);
    const int p0 = __popcll(B0 & below);
    const int p1 = c0 + __popcll(B1 & below);
    const int p2 = __popcll(B2 & below);
    const int p3 = c2 + __popcll(B3 & below);
    if (u[0] >= t) clo[p0] = ((u64)vmr[0] << 32) | (u64)__float_as_uint(a[0]);
    if (u[1] >= t) clo[p1] = ((u64)vmr[1] << 32) | (u64)__float_as_uint(a[1]);
    if (u[2] >= t) chi[p2] = ((u64)vmr[2] << 32) | (u64)__float_as_uint(a[2]);
    if (u[3] >= t) chi[p3] = ((u64)vmr[3] << 32) | (u64)__float_as_uint(a[3]);
    const int nlo = c0 + c1, nhi = c2 + c3;
    if (lane < 2)      clo[nlo + lane] = 0ull;        // zero pads (odd tail)
    else if (lane < 4) chi[nhi + lane - 2] = 0ull;
    asm volatile("s_waitcnt lgkmcnt(0)" ::: "memory");

    // sparse PV: lane (half,d) walks its half's compact list, j-ascending
    const int n = half ? nhi : nlo;
    const u64* cp = half ? chi : clo;
    const int gn = (n + 1) >> 1;
    float s = 0.0f;
    for (int g = 0; g < gn; ++g) {
      uint4 e = *(const uint4*)(cp + ((size_t)g << 1));  // (a0,vm0,a1,vm1)
      const u32 mk0 = (u32)__builtin_amdgcn_sbfe((int)e.y, d, 1);
      s = __fadd_rn(s, __uint_as_float(e.x & mk0));
      const u32 mk1 = (u32)__builtin_amdgcn_sbfe((int)e.w, d, 1);
      s = __fadd_rn(s, __uint_as_float(e.z & mk1));
    }
    s += __shfl_xor(s, 32, 64);     // half0: s_lo + s_hi (ref order)
    if (half == 0)
      outPV[(((size_t)tbh << 8) + i) * 32 + d] = s;
  }
}

// ---------------------------------------------------------------------------
// attn_lif: LIF over T on PV output, [T,B,H,N,D] -> [T,B,N,C] transpose.
// ---------------------------------------------------------------------------
__global__ __launch_bounds__(256) void attn_lif(
    const float* __restrict__ pv, float* __restrict__ sout)
{
  const int blk = blockIdx.x;          // b*256 + n
  const int b = blk >> 8, n = blk & 255;
  const int c = threadIdx.x;
  const int hh = c >> 5, d = c & 31;
  float v = 0.0f;
#pragma unroll
  for (int t = 0; t < 4; ++t) {
    float xv = pv[(((size_t)(t * 16 + b) * 8 + hh) << 13) + (n << 5) + d];
    v = __fadd_rn(v, __fmul_rn(__fsub_rn(xv, v), 0.5f));
    bool s = (v >= 1.0f);
    sout[(((size_t)(t * 16 + b) << 8) + n) * 256 + c] = s ? 1.0f : 0.0f;
    v = s ? 0.0f : v;
  }
}

// ---------------------------------------------------------------------------
// Final LIF: hproj [T,B,N,C] -> d_out spikes [T,B,N,C]
// ---------------------------------------------------------------------------
__global__ __launch_bounds__(256) void final_lif(
    const float* __restrict__ hp, float* __restrict__ out)
{
  const size_t base = (size_t)blockIdx.x * 256 + threadIdx.x;
  float v = 0.0f;
#pragma unroll
  for (int t = 0; t < 4; ++t) {
    float xv = hp[base + (size_t)t * BNC_];
    v = __fadd_rn(v, __fmul_rn(__fsub_rn(xv, v), 0.5f));
    bool s = (v >= 1.0f);
    out[base + (size_t)t * BNC_] = s ? 1.0f : 0.0f;
    v = s ? 0.0f : v;
  }
}

// ---------------------------------------------------------------------------
extern "C" void kernel_launch(void* const* d_in, const int* in_sizes, int n_in,
                              void* d_out, int out_size, void* d_ws, size_t ws_size,
                              hipStream_t stream) {
  const float* x       = (const float*)d_in[0];
  const float* wq      = (const float*)d_in[1];
  const float* wk      = (const float*)d_in[2];
  const float* wv      = (const float*)d_in[3];
  const float* bnq     = (const float*)d_in[4];
  const float* bnk     = (const float*)d_in[5];
  const float* bnv     = (const float*)d_in[6];
  const float* proj_w  = (const float*)d_in[7];
  const float* proj_bn = (const float*)d_in[8];
  const float* rtable  = (const float*)d_in[9];
  float* out = (float*)d_out;

  float* ws = (float*)d_ws;
  float* hq = ws;                  // NELEM floats
  float* hk = ws + (size_t)NELEM;
  float* hv = ws + (size_t)NELEM * 2;
  u32* mq = (u32*)(ws + (size_t)NELEM * 3);   // 131072 u32 each
  u32* mk = mq + 131072;
  u32* mv = mk + 131072;
  float* outPV = hq;   // reuse: hq dead after mask extraction
  float* sout  = hk;
  float* hproj = hv;

  dim3 ggrid(4, 128);   // (N/64, M/128)
  gemm_bn_f<3><<<ggrid, 256, 0, stream>>>(x, wq, wk, wv, bnq, bnk, bnv,
                                          hq, hk, hv);

  lif_pack3<<<dim3(4096, 3), 256, 0, stream>>>(hq, hk, hv, mq, mk, mv);

  attn_topk_pv<<<dim3(512, 8), 256, 0, stream>>>(mq, mk, mv, rtable, outPV);

  attn_lif<<<4096, 256, 0, stream>>>(outPV, sout);

  gemm_bn_f<1><<<ggrid, 256, 0, stream>>>(sout, proj_w, proj_w, proj_w,
                                          proj_bn, proj_bn, proj_bn,
                                          hproj, hproj, hproj);

  final_lif<<<4096, 256, 0, stream>>>(hproj, out);
}

// Round 6
// 695.281 us; speedup vs baseline: 2.1607x; 2.1607x over previous
//
#include <hip/hip_runtime.h>

typedef unsigned int u32;
typedef unsigned long long u64;

// Problem constants
#define T_ 4
#define B_ 16
#define N_ 256
#define C_ 256
#define H_ 8
#define D_ 32
#define BNC_ 1048576   // B*N*C
#define NELEM 4194304  // T*B*N*C

// ---------------------------------------------------------------------------
// Fused multi-W GEMM + eval-BatchNorm.  O[w][m,o] = BN_w(sum_c A[m,c]*W[w][o,c])
// Round-6 fix: round-5's __launch_bounds__(256,2) clamped the allocator to
// 128 VGPRs < the ~180 the kernel needs -> acc spilled to scratch (3.5 GB HBM
// traffic, VALUBusy 4%). Bound removed; everything else identical.
// DS-amortization: per wave-kk, 5 ds_read_b128 feed 96 FMA instrs (NW=3).
// 128x64 tile, 256 thr, 8x4 micro, A double-buffered LDS (k-major),
// W single-buffered (2 barriers/slab), slab s+1 register-prefetched.
// FMA chain per output strictly k-ascending (bit-exact vs reference).
// ---------------------------------------------------------------------------
template<int NW>
__global__ __launch_bounds__(256) void gemm_bn_f(
    const float* __restrict__ A,
    const float* __restrict__ W0, const float* __restrict__ W1,
    const float* __restrict__ W2,
    const float* __restrict__ bn0, const float* __restrict__ bn1,
    const float* __restrict__ bn2,
    float* __restrict__ O0, float* __restrict__ O1, float* __restrict__ O2)
{
  __shared__ float As[2][32][132];     // [buf][k][row] k-major, 132 pad
  __shared__ float Ws[NW][32][68];     // [w][k][row]   k-major, 68 pad
  const int tid = threadIdx.x;
  const int m0 = blockIdx.y << 7;      // 128 rows
  const int n0 = blockIdx.x << 6;      // 64 cols
  const int tx = tid & 15;             // col group (4 cols)
  const int ty = tid >> 4;             // row group (8 rows)
  const int arow = tid >> 1, ak = (tid & 1) << 4;   // A loader: 1 row, 16 ks
  const int brow = tid >> 2, bk = (tid & 3) << 3;   // W loader: 1 row, 8 ks

  const float* Wp[3] = {W0, W1, W2};
  const float* bnp[3] = {bn0, bn1, bn2};
  float* Op[3] = {O0, O1, O2};

  const float* aP = A + (size_t)(m0 + arow) * 256 + ak;
  const float* wP[3];
#pragma unroll
  for (int w = 0; w < NW; ++w) wP[w] = Wp[w] + (size_t)(n0 + brow) * 256 + bk;

  float acc[NW][8][4] = {};
  float4 pa[4]; float4 pw[NW][2];

  // ---- prologue: load + write slab 0
#pragma unroll
  for (int c = 0; c < 4; ++c) pa[c] = *(const float4*)(aP + (c << 2));
#pragma unroll
  for (int w = 0; w < NW; ++w)
#pragma unroll
    for (int c = 0; c < 2; ++c)
      pw[w][c] = *(const float4*)(wP[w] + (c << 2));
#pragma unroll
  for (int c = 0; c < 4; ++c) {
    As[0][ak + (c<<2) + 0][arow] = pa[c].x;
    As[0][ak + (c<<2) + 1][arow] = pa[c].y;
    As[0][ak + (c<<2) + 2][arow] = pa[c].z;
    As[0][ak + (c<<2) + 3][arow] = pa[c].w;
  }
#pragma unroll
  for (int w = 0; w < NW; ++w)
#pragma unroll
    for (int c = 0; c < 2; ++c) {
      Ws[w][bk + (c<<2) + 0][brow] = pw[w][c].x;
      Ws[w][bk + (c<<2) + 1][brow] = pw[w][c].y;
      Ws[w][bk + (c<<2) + 2][brow] = pw[w][c].z;
      Ws[w][bk + (c<<2) + 3][brow] = pw[w][c].w;
    }
  __syncthreads();

  int cur = 0;
  for (int s = 0; s < 8; ++s) {
    if (s < 7) {                      // prefetch slab s+1 into regs
      const int k0 = (s + 1) << 5;
#pragma unroll
      for (int c = 0; c < 4; ++c) pa[c] = *(const float4*)(aP + k0 + (c << 2));
#pragma unroll
      for (int w = 0; w < NW; ++w)
#pragma unroll
        for (int c = 0; c < 2; ++c)
          pw[w][c] = *(const float4*)(wP[w] + k0 + (c << 2));
    }
#pragma unroll
    for (int kk = 0; kk < 32; ++kk) {
      const float4 a0 = *(const float4*)&As[cur][kk][ty << 3];
      const float4 a1 = *(const float4*)&As[cur][kk][(ty << 3) + 4];
      const float ar[8] = {a0.x, a0.y, a0.z, a0.w, a1.x, a1.y, a1.z, a1.w};
#pragma unroll
      for (int w = 0; w < NW; ++w) {
        const float4 b4 = *(const float4*)&Ws[w][kk][tx << 2];
        const float br[4] = {b4.x, b4.y, b4.z, b4.w};
#pragma unroll
        for (int ii = 0; ii < 8; ++ii)
#pragma unroll
          for (int jj = 0; jj < 4; ++jj)
            acc[w][ii][jj] = fmaf(ar[ii], br[jj], acc[w][ii][jj]);
      }
    }
    if (s < 7) {
      __syncthreads();                // all waves done reading slab s
#pragma unroll
      for (int c = 0; c < 4; ++c) {
        As[cur ^ 1][ak + (c<<2) + 0][arow] = pa[c].x;
        As[cur ^ 1][ak + (c<<2) + 1][arow] = pa[c].y;
        As[cur ^ 1][ak + (c<<2) + 2][arow] = pa[c].z;
        As[cur ^ 1][ak + (c<<2) + 3][arow] = pa[c].w;
      }
#pragma unroll
      for (int w = 0; w < NW; ++w)
#pragma unroll
        for (int c = 0; c < 2; ++c) {
          Ws[w][bk + (c<<2) + 0][brow] = pw[w][c].x;
          Ws[w][bk + (c<<2) + 1][brow] = pw[w][c].y;
          Ws[w][bk + (c<<2) + 2][brow] = pw[w][c].z;
          Ws[w][bk + (c<<2) + 3][brow] = pw[w][c].w;
        }
      __syncthreads();                // slab s+1 visible
      cur ^= 1;
    }
  }

  // ---- BN epilogue (identical op sequence to rounds 1-4, absmax 0.0)
#pragma unroll
  for (int w = 0; w < NW; ++w) {
    const float* gma = bnp[w];
    const float* bta = bnp[w] + 256;
    const float* mea = bnp[w] + 512;
    const float* vra = bnp[w] + 768;
    float sc[4], me[4], be[4];
#pragma unroll
    for (int jj = 0; jj < 4; ++jj) {
      int o = n0 + (tx << 2) + jj;
      sc[jj] = __fmul_rn(gma[o], 1.0f / sqrtf(__fadd_rn(vra[o], 1e-5f)));
      me[jj] = mea[o];
      be[jj] = bta[o];
    }
#pragma unroll
    for (int ii = 0; ii < 8; ++ii) {
      int row = m0 + (ty << 3) + ii;
      float4 y;
      y.x = __fadd_rn(__fmul_rn(__fsub_rn(acc[w][ii][0], me[0]), sc[0]), be[0]);
      y.y = __fadd_rn(__fmul_rn(__fsub_rn(acc[w][ii][1], me[1]), sc[1]), be[1]);
      y.z = __fadd_rn(__fmul_rn(__fsub_rn(acc[w][ii][2], me[2]), sc[2]), be[2]);
      y.w = __fadd_rn(__fmul_rn(__fsub_rn(acc[w][ii][3], me[3]), sc[3]), be[3]);
      *(float4*)(Op[w] + (size_t)row * 256 + n0 + (tx << 2)) = y;
    }
  }
}

// ---------------------------------------------------------------------------
// LIF over T (TAU=2, hard reset) + pack spikes into per-head 32-bit masks.
// ---------------------------------------------------------------------------
__global__ __launch_bounds__(256) void lif_pack3(
    const float* __restrict__ h0, const float* __restrict__ h1,
    const float* __restrict__ h2,
    u32* __restrict__ m0p, u32* __restrict__ m1p, u32* __restrict__ m2p)
{
  const float* h = (blockIdx.y == 0) ? h0 : (blockIdx.y == 1) ? h1 : h2;
  u32* mask      = (blockIdx.y == 0) ? m0p : (blockIdx.y == 1) ? m1p : m2p;
  const int blk = blockIdx.x;          // b*256 + n
  const int b = blk >> 8, n = blk & 255;
  const int c = threadIdx.x;
  const int wave = c >> 6, lane = c & 63;
  const size_t idx = ((size_t)b * 256 + n) * 256 + c;
  float v = 0.0f;
#pragma unroll
  for (int t = 0; t < 4; ++t) {
    float xv = h[idx + (size_t)t * BNC_];
    v = __fadd_rn(v, __fmul_rn(__fsub_rn(xv, v), 0.5f));
    bool s = (v >= 1.0f);
    u64 bal = __ballot(s);
    const int h0i = wave << 1;
    u32* mptr = mask + ((size_t)(t * 16 + b) * 8) * 256 + n;
    if (lane == 0)  mptr[(size_t)h0i * 256]       = (u32)bal;
    if (lane == 32) mptr[(size_t)(h0i + 1) * 256] = (u32)(bal >> 32);
    v = s ? 0.0f : v;
  }
}

// ---------------------------------------------------------------------------
// Fused attention: QK^T (popcount) + rel-bias + exact top-64 + sparse PV.
// (unchanged from round 4: 90 us, VALUBusy 83%)
// ---------------------------------------------------------------------------
__global__ __launch_bounds__(256) void attn_topk_pv(
    const u32* __restrict__ qmask, const u32* __restrict__ kmask,
    const u32* __restrict__ vmask, const float* __restrict__ table,
    float* __restrict__ outPV)
{
  __shared__ __align__(16) float bias[511];
  __shared__ __align__(16) u64 comp[4][2][132];  // [wave][half][entries]

  const int tbh = blockIdx.x;
  const int rg = blockIdx.y;
  const int hh = tbh & 7;
  const int tid = threadIdx.x;

  bias[tid] = table[tid * 8 + hh];
  if (tid < 255) bias[256 + tid] = table[(256 + tid) * 8 + hh];
  __syncthreads();

  const int wave = tid >> 6, lane = tid & 63;
  const int d = lane & 31, half = lane >> 5;

  // row-invariant per-lane K/V mask words (j = lane + 64r)
  u32 kmr[4], vmr[4];
#pragma unroll
  for (int r = 0; r < 4; ++r) {
    kmr[r] = kmask[((size_t)tbh << 8) + lane + (r << 6)];
    vmr[r] = vmask[((size_t)tbh << 8) + lane + (r << 6)];
  }
  const u64 below = (1ull << lane) - 1ull;
  u64* const clo = &comp[wave][0][0];
  u64* const chi = &comp[wave][1][0];

#pragma unroll 1
  for (int it = 0; it < 8; ++it) {
    const int i = (rg << 5) + (it << 2) + wave;
    const u32 qm = qmask[((size_t)tbh << 8) + i];
    float a[4]; u32 u[4];
#pragma unroll
    for (int r = 0; r < 4; ++r) {
      const int j = lane + (r << 6);
      const int m = __popc(qm & kmr[r]);
      float av = __fmul_rn((float)m, 0.0625f);     // * C^-0.5 = 1/16 exact
      av = __fadd_rn(av, bias[j - i + 255]);        // one rounded add == ref
      a[r] = av;
      const u32 bb = __float_as_uint(av);
      u[r] = bb ^ ((u32)((int)bb >> 31) | 0x80000000u);
    }
    // MSB-greedy exact 64th-largest; early exit when keep-set pinned
    u32 t = 0u;
    for (int bit = 31; bit >= 0; --bit) {
      const u32 cand = t | (1u << bit);
      const int cnt = __popcll(__ballot(u[0] >= cand)) +
                      __popcll(__ballot(u[1] >= cand)) +
                      __popcll(__ballot(u[2] >= cand)) +
                      __popcll(__ballot(u[3] >= cand));
      if (cnt >= 64) { t = cand; if (cnt == 64) break; }
    }
    // keep ballots -> compaction positions (j-ascending per half)
    const u64 B0 = __ballot(u[0] >= t), B1 = __ballot(u[1] >= t);
    const u64 B2 = __ballot(u[2] >= t), B3 = __ballot(u[3] >= t);
    const int c0 = __popcll(B0), c1 = __popcll(B1);
    const int c2 = __popcll(B2), c3 = __popcll(B3);
    const int p0 = __popcll(B0 & below);
    const int p1 = c0 + __popcll(B1 & below);
    const int p2 = __popcll(B2 & below);
    const int p3 = c2 + __popcll(B3 & below);
    if (u[0] >= t) clo[p0] = ((u64)vmr[0] << 32) | (u64)__float_as_uint(a[0]);
    if (u[1] >= t) clo[p1] = ((u64)vmr[1] << 32) | (u64)__float_as_uint(a[1]);
    if (u[2] >= t) chi[p2] = ((u64)vmr[2] << 32) | (u64)__float_as_uint(a[2]);
    if (u[3] >= t) chi[p3] = ((u64)vmr[3] << 32) | (u64)__float_as_uint(a[3]);
    const int nlo = c0 + c1, nhi = c2 + c3;
    if (lane < 2)      clo[nlo + lane] = 0ull;        // zero pads (odd tail)
    else if (lane < 4) chi[nhi + lane - 2] = 0ull;
    asm volatile("s_waitcnt lgkmcnt(0)" ::: "memory");

    // sparse PV: lane (half,d) walks its half's compact list, j-ascending
    const int n = half ? nhi : nlo;
    const u64* cp = half ? chi : clo;
    const int gn = (n + 1) >> 1;
    float s = 0.0f;
    for (int g = 0; g < gn; ++g) {
      uint4 e = *(const uint4*)(cp + ((size_t)g << 1));  // (a0,vm0,a1,vm1)
      const u32 mk0 = (u32)__builtin_amdgcn_sbfe((int)e.y, d, 1);
      s = __fadd_rn(s, __uint_as_float(e.x & mk0));
      const u32 mk1 = (u32)__builtin_amdgcn_sbfe((int)e.w, d, 1);
      s = __fadd_rn(s, __uint_as_float(e.z & mk1));
    }
    s += __shfl_xor(s, 32, 64);     // half0: s_lo + s_hi (ref order)
    if (half == 0)
      outPV[(((size_t)tbh << 8) + i) * 32 + d] = s;
  }
}

// ---------------------------------------------------------------------------
// attn_lif: LIF over T on PV output, [T,B,H,N,D] -> [T,B,N,C] transpose.
// ---------------------------------------------------------------------------
__global__ __launch_bounds__(256) void attn_lif(
    const float* __restrict__ pv, float* __restrict__ sout)
{
  const int blk = blockIdx.x;          // b*256 + n
  const int b = blk >> 8, n = blk & 255;
  const int c = threadIdx.x;
  const int hh = c >> 5, d = c & 31;
  float v = 0.0f;
#pragma unroll
  for (int t = 0; t < 4; ++t) {
    float xv = pv[(((size_t)(t * 16 + b) * 8 + hh) << 13) + (n << 5) + d];
    v = __fadd_rn(v, __fmul_rn(__fsub_rn(xv, v), 0.5f));
    bool s = (v >= 1.0f);
    sout[(((size_t)(t * 16 + b) << 8) + n) * 256 + c] = s ? 1.0f : 0.0f;
    v = s ? 0.0f : v;
  }
}

// ---------------------------------------------------------------------------
// Final LIF: hproj [T,B,N,C] -> d_out spikes [T,B,N,C]
// ---------------------------------------------------------------------------
__global__ __launch_bounds__(256) void final_lif(
    const float* __restrict__ hp, float* __restrict__ out)
{
  const size_t base = (size_t)blockIdx.x * 256 + threadIdx.x;
  float v = 0.0f;
#pragma unroll
  for (int t = 0; t < 4; ++t) {
    float xv = hp[base + (size_t)t * BNC_];
    v = __fadd_rn(v, __fmul_rn(__fsub_rn(xv, v), 0.5f));
    bool s = (v >= 1.0f);
    out[base + (size_t)t * BNC_] = s ? 1.0f : 0.0f;
    v = s ? 0.0f : v;
  }
}

// ---------------------------------------------------------------------------
extern "C" void kernel_launch(void* const* d_in, const int* in_sizes, int n_in,
                              void* d_out, int out_size, void* d_ws, size_t ws_size,
                              hipStream_t stream) {
  const float* x       = (const float*)d_in[0];
  const float* wq      = (const float*)d_in[1];
  const float* wk      = (const float*)d_in[2];
  const float* wv      = (const float*)d_in[3];
  const float* bnq     = (const float*)d_in[4];
  const float* bnk     = (const float*)d_in[5];
  const float* bnv     = (const float*)d_in[6];
  const float* proj_w  = (const float*)d_in[7];
  const float* proj_bn = (const float*)d_in[8];
  const float* rtable  = (const float*)d_in[9];
  float* out = (float*)d_out;

  float* ws = (float*)d_ws;
  float* hq = ws;                  // NELEM floats
  float* hk = ws + (size_t)NELEM;
  float* hv = ws + (size_t)NELEM * 2;
  u32* mq = (u32*)(ws + (size_t)NELEM * 3);   // 131072 u32 each
  u32* mk = mq + 131072;
  u32* mv = mk + 131072;
  float* outPV = hq;   // reuse: hq dead after mask extraction
  float* sout  = hk;
  float* hproj = hv;

  dim3 ggrid(4, 128);   // (N/64, M/128)
  gemm_bn_f<3><<<ggrid, 256, 0, stream>>>(x, wq, wk, wv, bnq, bnk, bnv,
                                          hq, hk, hv);

  lif_pack3<<<dim3(4096, 3), 256, 0, stream>>>(hq, hk, hv, mq, mk, mv);

  attn_topk_pv<<<dim3(512, 8), 256, 0, stream>>>(mq, mk, mv, rtable, outPV);

  attn_lif<<<4096, 256, 0, stream>>>(outPV, sout);

  gemm_bn_f<1><<<ggrid, 256, 0, stream>>>(sout, proj_w, proj_w, proj_w,
                                          proj_bn, proj_bn, proj_bn,
                                          hproj, hproj, hproj);

  final_lif<<<4096, 256, 0, stream>>>(hproj, out);
}

// Round 12
// 436.977 us; speedup vs baseline: 3.4380x; 1.5911x over previous
//
#include <hip/hip_runtime.h>

typedef unsigned int u32;
typedef unsigned long long u64;

// Problem constants
#define T_ 4
#define B_ 16
#define N_ 256
#define C_ 256
#define H_ 8
#define D_ 32
#define BNC_ 1048576   // B*N*C
#define NELEM 4194304  // T*B*N*C

// ---------------------------------------------------------------------------
// transpose4: WT[z][c][o] = W[z][o][c] for the 4 weight matrices.
// Enables wave-uniform float4 B-loads in the GEMM (B never touches LDS/VGPR
// bulk). 2 MB traffic total, ~5 us.
// ---------------------------------------------------------------------------
__global__ __launch_bounds__(256) void transpose4(
    const float* __restrict__ w0, const float* __restrict__ w1,
    const float* __restrict__ w2, const float* __restrict__ w3,
    float* __restrict__ wt)
{
  __shared__ float t[32][33];
  const float* src = (blockIdx.z == 0) ? w0 : (blockIdx.z == 1) ? w1
                   : (blockIdx.z == 2) ? w2 : w3;
  float* dst = wt + ((size_t)blockIdx.z << 16);
  const int lx = threadIdx.x & 31, ly = threadIdx.x >> 5;
  const int x = (blockIdx.x << 5) + lx;
  const int y0 = (blockIdx.y << 5) + ly;
#pragma unroll
  for (int r = 0; r < 32; r += 8)
    t[ly + r][lx] = src[(size_t)(y0 + r) * 256 + x];
  __syncthreads();
  const int xo = (blockIdx.y << 5) + lx;
  const int yo = (blockIdx.x << 5) + ly;
#pragma unroll
  for (int r = 0; r < 32; r += 8)
    dst[(size_t)(yo + r) * 256 + xo] = t[lx][ly + r];
}

// ---------------------------------------------------------------------------
// GEMM + eval-BN, B-operand via wave-uniform L1 broadcast loads.
// O[w][m,o] = BN_w(sum_c A[m,c] * WT[w][c,o])
// Wave owns ALL 256 rows of the block x CW cols (cols wave-uniform).
// Lane = 4 consecutive rows -> one ds_read_b128 of k-major A per kk (12 DS
// cyc) feeding NW*16 FMAs (96 VALU cyc at NW=3) -> VALU-bound at last.
// B: float4 broadcast load from transposed W (L1-resident, 0 DS, ~4 VGPR;
// wave-uniform address -> compiler can scalarize to s_load).
// acc = NW*4*CW regs (48 QKV / 32 proj) -> no spill (round-5/6 failure mode).
// FMA chain per output strictly k-ascending (bit-exact vs reference).
// ---------------------------------------------------------------------------
template<int NW, int CW>
__global__ __launch_bounds__(256) void gemm_bn_t(
    const float* __restrict__ A, const float* __restrict__ WTb,
    const float* __restrict__ bn0, const float* __restrict__ bn1,
    const float* __restrict__ bn2,
    float* __restrict__ O0, float* __restrict__ O1, float* __restrict__ O2)
{
  __shared__ float As[32][260];        // k-major, stride 1040B (16B-aligned)
  const int tid = threadIdx.x;
  const int wave = tid >> 6, lane = tid & 63;
  const int m0 = blockIdx.y << 8;                       // 256 rows/block
  const int col0 = blockIdx.x * (4 * CW) + wave * CW;   // wave-uniform cols
  const int sr = tid >> 3;             // staging row base 0..31
  const int sk = (tid & 7) << 2;       // staging k 0,4,...,28
  const int row4 = lane << 2;          // lane's rows: row4..row4+3

  const float* bnp[3] = {bn0, bn1, bn2};
  float* Op[3] = {O0, O1, O2};

  float acc[NW][4][CW] = {};

  for (int s = 0; s < 8; ++s) {
    const int k0 = s << 5;
    float4 pa[8];
#pragma unroll
    for (int c = 0; c < 8; ++c)
      pa[c] = *(const float4*)(A + (size_t)(m0 + sr + (c << 5)) * 256 + k0 + sk);
    __syncthreads();                   // all waves done reading slab s-1
#pragma unroll
    for (int c = 0; c < 8; ++c) {
      As[sk + 0][sr + (c << 5)] = pa[c].x;
      As[sk + 1][sr + (c << 5)] = pa[c].y;
      As[sk + 2][sr + (c << 5)] = pa[c].z;
      As[sk + 3][sr + (c << 5)] = pa[c].w;
    }
    __syncthreads();                   // slab s visible
#pragma unroll 4
    for (int kk = 0; kk < 32; ++kk) {
      const float4 av = *(const float4*)&As[kk][row4];
      const float ar[4] = {av.x, av.y, av.z, av.w};
#pragma unroll
      for (int w = 0; w < NW; ++w) {
#pragma unroll
        for (int cq = 0; cq < CW / 4; ++cq) {
          const float4 b4 = *(const float4*)(
              WTb + ((size_t)w << 16) + (size_t)(k0 + kk) * 256 + col0 + (cq << 2));
          const float br[4] = {b4.x, b4.y, b4.z, b4.w};
#pragma unroll
          for (int r = 0; r < 4; ++r)
#pragma unroll
            for (int j = 0; j < 4; ++j)
              acc[w][r][(cq << 2) + j] =
                  fmaf(ar[r], br[j], acc[w][r][(cq << 2) + j]);
        }
      }
    }
  }

  // ---- BN epilogue (identical op sequence to rounds 1-6, absmax 0.0)
#pragma unroll
  for (int w = 0; w < NW; ++w) {
    float sc[CW], me[CW], be[CW];
#pragma unroll
    for (int j = 0; j < CW; ++j) {
      const int o = col0 + j;
      sc[j] = __fmul_rn(bnp[w][o], 1.0f / sqrtf(__fadd_rn(bnp[w][768 + o], 1e-5f)));
      me[j] = bnp[w][512 + o];
      be[j] = bnp[w][256 + o];
    }
#pragma unroll
    for (int r = 0; r < 4; ++r) {
      float* outp = Op[w] + (size_t)(m0 + row4 + r) * 256 + col0;
#pragma unroll
      for (int cq = 0; cq < CW / 4; ++cq) {
        float4 y;
        y.x = __fadd_rn(__fmul_rn(__fsub_rn(acc[w][r][cq*4+0], me[cq*4+0]), sc[cq*4+0]), be[cq*4+0]);
        y.y = __fadd_rn(__fmul_rn(__fsub_rn(acc[w][r][cq*4+1], me[cq*4+1]), sc[cq*4+1]), be[cq*4+1]);
        y.z = __fadd_rn(__fmul_rn(__fsub_rn(acc[w][r][cq*4+2], me[cq*4+2]), sc[cq*4+2]), be[cq*4+2]);
        y.w = __fadd_rn(__fmul_rn(__fsub_rn(acc[w][r][cq*4+3], me[cq*4+3]), sc[cq*4+3]), be[cq*4+3]);
        *(float4*)(outp + (cq << 2)) = y;
      }
    }
  }
}

// ---------------------------------------------------------------------------
// LIF over T (TAU=2, hard reset) + pack spikes into per-head 32-bit masks.
// ---------------------------------------------------------------------------
__global__ __launch_bounds__(256) void lif_pack3(
    const float* __restrict__ h0, const float* __restrict__ h1,
    const float* __restrict__ h2,
    u32* __restrict__ m0p, u32* __restrict__ m1p, u32* __restrict__ m2p)
{
  const float* h = (blockIdx.y == 0) ? h0 : (blockIdx.y == 1) ? h1 : h2;
  u32* mask      = (blockIdx.y == 0) ? m0p : (blockIdx.y == 1) ? m1p : m2p;
  const int blk = blockIdx.x;          // b*256 + n
  const int b = blk >> 8, n = blk & 255;
  const int c = threadIdx.x;
  const int wave = c >> 6, lane = c & 63;
  const size_t idx = ((size_t)b * 256 + n) * 256 + c;
  float v = 0.0f;
#pragma unroll
  for (int t = 0; t < 4; ++t) {
    float xv = h[idx + (size_t)t * BNC_];
    v = __fadd_rn(v, __fmul_rn(__fsub_rn(xv, v), 0.5f));
    bool s = (v >= 1.0f);
    u64 bal = __ballot(s);
    const int h0i = wave << 1;
    u32* mptr = mask + ((size_t)(t * 16 + b) * 8) * 256 + n;
    if (lane == 0)  mptr[(size_t)h0i * 256]       = (u32)bal;
    if (lane == 32) mptr[(size_t)(h0i + 1) * 256] = (u32)(bal >> 32);
    v = s ? 0.0f : v;
  }
}

// ---------------------------------------------------------------------------
// Fused attention: QK^T (popcount) + rel-bias + exact top-64 + sparse PV.
// (unchanged from round 4: 90 us, VALUBusy 83%)
// ---------------------------------------------------------------------------
__global__ __launch_bounds__(256) void attn_topk_pv(
    const u32* __restrict__ qmask, const u32* __restrict__ kmask,
    const u32* __restrict__ vmask, const float* __restrict__ table,
    float* __restrict__ outPV)
{
  __shared__ __align__(16) float bias[511];
  __shared__ __align__(16) u64 comp[4][2][132];  // [wave][half][entries]

  const int tbh = blockIdx.x;
  const int rg = blockIdx.y;
  const int hh = tbh & 7;
  const int tid = threadIdx.x;

  bias[tid] = table[tid * 8 + hh];
  if (tid < 255) bias[256 + tid] = table[(256 + tid) * 8 + hh];
  __syncthreads();

  const int wave = tid >> 6, lane = tid & 63;
  const int d = lane & 31, half = lane >> 5;

  // row-invariant per-lane K/V mask words (j = lane + 64r)
  u32 kmr[4], vmr[4];
#pragma unroll
  for (int r = 0; r < 4; ++r) {
    kmr[r] = kmask[((size_t)tbh << 8) + lane + (r << 6)];
    vmr[r] = vmask[((size_t)tbh << 8) + lane + (r << 6)];
  }
  const u64 below = (1ull << lane) - 1ull;
  u64* const clo = &comp[wave][0][0];
  u64* const chi = &comp[wave][1][0];

#pragma unroll 1
  for (int it = 0; it < 8; ++it) {
    const int i = (rg << 5) + (it << 2) + wave;
    const u32 qm = qmask[((size_t)tbh << 8) + i];
    float a[4]; u32 u[4];
#pragma unroll
    for (int r = 0; r < 4; ++r) {
      const int j = lane + (r << 6);
      const int m = __popc(qm & kmr[r]);
      float av = __fmul_rn((float)m, 0.0625f);     // * C^-0.5 = 1/16 exact
      av = __fadd_rn(av, bias[j - i + 255]);        // one rounded add == ref
      a[r] = av;
      const u32 bb = __float_as_uint(av);
      u[r] = bb ^ ((u32)((int)bb >> 31) | 0x80000000u);
    }
    // MSB-greedy exact 64th-largest; early exit when keep-set pinned
    u32 t = 0u;
    for (int bit = 31; bit >= 0; --bit) {
      const u32 cand = t | (1u << bit);
      const int cnt = __popcll(__ballot(u[0] >= cand)) +
                      __popcll(__ballot(u[1] >= cand)) +
                      __popcll(__ballot(u[2] >= cand)) +
                      __popcll(__ballot(u[3] >= cand));
      if (cnt >= 64) { t = cand; if (cnt == 64) break; }
    }
    // keep ballots -> compaction positions (j-ascending per half)
    const u64 B0 = __ballot(u[0] >= t), B1 = __ballot(u[1] >= t);
    const u64 B2 = __ballot(u[2] >= t), B3 = __ballot(u[3] >= t);
    const int c0 = __popcll(B0), c1 = __popcll(B1);
    const int c2 = __popcll(B2), c3 = __popcll(B3);
    const int p0 = __popcll(B0 & below);
    const int p1 = c0 + __popcll(B1 & below);
    const int p2 = __popcll(B2 & below);
    const int p3 = c2 + __popcll(B3 & below);
    if (u[0] >= t) clo[p0] = ((u64)vmr[0] << 32) | (u64)__float_as_uint(a[0]);
    if (u[1] >= t) clo[p1] = ((u64)vmr[1] << 32) | (u64)__float_as_uint(a[1]);
    if (u[2] >= t) chi[p2] = ((u64)vmr[2] << 32) | (u64)__float_as_uint(a[2]);
    if (u[3] >= t) chi[p3] = ((u64)vmr[3] << 32) | (u64)__float_as_uint(a[3]);
    const int nlo = c0 + c1, nhi = c2 + c3;
    if (lane < 2)      clo[nlo + lane] = 0ull;        // zero pads (odd tail)
    else if (lane < 4) chi[nhi + lane - 2] = 0ull;
    asm volatile("s_waitcnt lgkmcnt(0)" ::: "memory");

    // sparse PV: lane (half,d) walks its half's compact list, j-ascending
    const int n = half ? nhi : nlo;
    const u64* cp = half ? chi : clo;
    const int gn = (n + 1) >> 1;
    float s = 0.0f;
    for (int g = 0; g < gn; ++g) {
      uint4 e = *(const uint4*)(cp + ((size_t)g << 1));  // (a0,vm0,a1,vm1)
      const u32 mk0 = (u32)__builtin_amdgcn_sbfe((int)e.y, d, 1);
      s = __fadd_rn(s, __uint_as_float(e.x & mk0));
      const u32 mk1 = (u32)__builtin_amdgcn_sbfe((int)e.w, d, 1);
      s = __fadd_rn(s, __uint_as_float(e.z & mk1));
    }
    s += __shfl_xor(s, 32, 64);     // half0: s_lo + s_hi (ref order)
    if (half == 0)
      outPV[(((size_t)tbh << 8) + i) * 32 + d] = s;
  }
}

// ---------------------------------------------------------------------------
// attn_lif: LIF over T on PV output, [T,B,H,N,D] -> [T,B,N,C] transpose.
// ---------------------------------------------------------------------------
__global__ __launch_bounds__(256) void attn_lif(
    const float* __restrict__ pv, float* __restrict__ sout)
{
  const int blk = blockIdx.x;          // b*256 + n
  const int b = blk >> 8, n = blk & 255;
  const int c = threadIdx.x;
  const int hh = c >> 5, d = c & 31;
  float v = 0.0f;
#pragma unroll
  for (int t = 0; t < 4; ++t) {
    float xv = pv[(((size_t)(t * 16 + b) * 8 + hh) << 13) + (n << 5) + d];
    v = __fadd_rn(v, __fmul_rn(__fsub_rn(xv, v), 0.5f));
    bool s = (v >= 1.0f);
    sout[(((size_t)(t * 16 + b) << 8) + n) * 256 + c] = s ? 1.0f : 0.0f;
    v = s ? 0.0f : v;
  }
}

// ---------------------------------------------------------------------------
// Final LIF: hproj [T,B,N,C] -> d_out spikes [T,B,N,C]
// ---------------------------------------------------------------------------
__global__ __launch_bounds__(256) void final_lif(
    const float* __restrict__ hp, float* __restrict__ out)
{
  const size_t base = (size_t)blockIdx.x * 256 + threadIdx.x;
  float v = 0.0f;
#pragma unroll
  for (int t = 0; t < 4; ++t) {
    float xv = hp[base + (size_t)t * BNC_];
    v = __fadd_rn(v, __fmul_rn(__fsub_rn(xv, v), 0.5f));
    bool s = (v >= 1.0f);
    out[base + (size_t)t * BNC_] = s ? 1.0f : 0.0f;
    v = s ? 0.0f : v;
  }
}

// ---------------------------------------------------------------------------
extern "C" void kernel_launch(void* const* d_in, const int* in_sizes, int n_in,
                              void* d_out, int out_size, void* d_ws, size_t ws_size,
                              hipStream_t stream) {
  const float* x       = (const float*)d_in[0];
  const float* wq      = (const float*)d_in[1];
  const float* wk      = (const float*)d_in[2];
  const float* wv      = (const float*)d_in[3];
  const float* bnq     = (const float*)d_in[4];
  const float* bnk     = (const float*)d_in[5];
  const float* bnv     = (const float*)d_in[6];
  const float* proj_w  = (const float*)d_in[7];
  const float* proj_bn = (const float*)d_in[8];
  const float* rtable  = (const float*)d_in[9];
  float* out = (float*)d_out;

  float* ws = (float*)d_ws;
  float* hq = ws;                  // NELEM floats
  float* hk = ws + (size_t)NELEM;
  float* hv = ws + (size_t)NELEM * 2;
  u32* mq = (u32*)(ws + (size_t)NELEM * 3);   // 131072 u32 each
  u32* mk = mq + 131072;
  u32* mv = mk + 131072;
  float* wt = (float*)(mv + 131072);          // 4 x 65536 floats (1 MB)
  float* outPV = hq;   // reuse: hq dead after mask extraction
  float* sout  = hk;
  float* hproj = hv;

  transpose4<<<dim3(8, 8, 4), 256, 0, stream>>>(wq, wk, wv, proj_w, wt);

  gemm_bn_t<3, 4><<<dim3(16, 64), 256, 0, stream>>>(
      x, wt, bnq, bnk, bnv, hq, hk, hv);

  lif_pack3<<<dim3(4096, 3), 256, 0, stream>>>(hq, hk, hv, mq, mk, mv);

  attn_topk_pv<<<dim3(512, 8), 256, 0, stream>>>(mq, mk, mv, rtable, outPV);

  attn_lif<<<4096, 256, 0, stream>>>(outPV, sout);

  gemm_bn_t<1, 8><<<dim3(8, 64), 256, 0, stream>>>(
      sout, wt + 3 * 65536, proj_bn, proj_bn, proj_bn, hproj, hproj, hproj);

  final_lif<<<4096, 256, 0, stream>>>(hproj, out);
}

// Round 13
// 321.470 us; speedup vs baseline: 4.6733x; 1.3593x over previous
//
#include <hip/hip_runtime.h>

typedef unsigned int u32;
typedef unsigned long long u64;

// Problem constants
#define T_ 4
#define B_ 16
#define N_ 256
#define C_ 256
#define H_ 8
#define D_ 32
#define BNC_ 1048576   // B*N*C
#define NELEM 4194304  // T*B*N*C

// ---------------------------------------------------------------------------
// GEMM + eval-BN. O[w][m,o] = BN_w(sum_c A[m,c] * W_w[o,c])
// Round-13: round-12's "wave-uniform B broadcast" never scalarized (compiler
// can't prove tid>>6 uniform) -> 768 per-lane VMEM loads/thread, latency-
// bound at VALUBusy 24%. Fix: stage the block's W slab in LDS (6 KB QKV /
// 4 KB proj) per k-slab; B-read becomes a uniform-address LDS broadcast
// (no VMEM latency, no registers). W staged directly from original [o][c]
// layout -> transpose4 kernel and wt buffer deleted.
// Values and FMA order bit-identical to rounds 7-12 (absmax 0.0).
// ---------------------------------------------------------------------------
template<int NW, int CW>
__global__ __launch_bounds__(256) void gemm_bn_l(
    const float* __restrict__ A,
    const float* __restrict__ W0, const float* __restrict__ W1,
    const float* __restrict__ W2,
    const float* __restrict__ bn0, const float* __restrict__ bn1,
    const float* __restrict__ bn2,
    float* __restrict__ O0, float* __restrict__ O1, float* __restrict__ O2)
{
  constexpr int NCOL = 4 * CW;         // cols per block (16 QKV / 32 proj)
  constexpr int WPT = NCOL / 8;        // staged W floats per thread per w
  __shared__ float As[32][260];        // k-major, stride 1040B
  __shared__ float Ws[NW][32][NCOL];   // [w][kk][col]
  const int tid = threadIdx.x;
  const int wave = tid >> 6, lane = tid & 63;
  const int m0 = blockIdx.y << 8;                 // 256 rows/block
  const int n0 = blockIdx.x * NCOL;
  const int col0 = n0 + wave * CW;                // wave's global col base
  const int sr = tid >> 3;             // A staging row base 0..31
  const int sk = (tid & 7) << 2;       // A staging k 0,4,...,28
  const int row4 = lane << 2;          // lane's rows: row4..row4+3

  const float* Wp[3] = {W0, W1, W2};
  const float* bnp[3] = {bn0, bn1, bn2};
  float* Op[3] = {O0, O1, O2};

  float acc[NW][4][CW] = {};

  for (int s = 0; s < 8; ++s) {
    const int k0 = s << 5;
    float4 pa[8];
#pragma unroll
    for (int c = 0; c < 8; ++c)
      pa[c] = *(const float4*)(A + (size_t)(m0 + sr + (c << 5)) * 256 + k0 + sk);
    // W slab -> regs (kk fastest in f for coalescing: col = f>>5, kk = f&31)
    float wb[NW][WPT];
#pragma unroll
    for (int w = 0; w < NW; ++w)
#pragma unroll
      for (int i = 0; i < WPT; ++i) {
        const int f = tid * WPT + i;
        const int col = f >> 5, kk = f & 31;
        wb[w][i] = Wp[w][(size_t)(n0 + col) * 256 + k0 + kk];
      }
    __syncthreads();                   // all waves done reading slab s-1
#pragma unroll
    for (int c = 0; c < 8; ++c) {
      As[sk + 0][sr + (c << 5)] = pa[c].x;
      As[sk + 1][sr + (c << 5)] = pa[c].y;
      As[sk + 2][sr + (c << 5)] = pa[c].z;
      As[sk + 3][sr + (c << 5)] = pa[c].w;
    }
#pragma unroll
    for (int w = 0; w < NW; ++w)
#pragma unroll
      for (int i = 0; i < WPT; ++i) {
        const int f = tid * WPT + i;
        Ws[w][f & 31][f >> 5] = wb[w][i];
      }
    __syncthreads();                   // slab s visible
#pragma unroll 4
    for (int kk = 0; kk < 32; ++kk) {
      const float4 av = *(const float4*)&As[kk][row4];
      const float ar[4] = {av.x, av.y, av.z, av.w};
#pragma unroll
      for (int w = 0; w < NW; ++w) {
#pragma unroll
        for (int cq = 0; cq < CW / 4; ++cq) {
          // uniform-address LDS broadcast (all lanes same addr, no conflict)
          const float4 b4 = *(const float4*)&Ws[w][kk][wave * CW + (cq << 2)];
          const float br[4] = {b4.x, b4.y, b4.z, b4.w};
#pragma unroll
          for (int r = 0; r < 4; ++r)
#pragma unroll
            for (int j = 0; j < 4; ++j)
              acc[w][r][(cq << 2) + j] =
                  fmaf(ar[r], br[j], acc[w][r][(cq << 2) + j]);
        }
      }
    }
  }

  // ---- BN epilogue (identical op sequence to rounds 1-12, absmax 0.0)
#pragma unroll
  for (int w = 0; w < NW; ++w) {
    float sc[CW], me[CW], be[CW];
#pragma unroll
    for (int j = 0; j < CW; ++j) {
      const int o = col0 + j;
      sc[j] = __fmul_rn(bnp[w][o], 1.0f / sqrtf(__fadd_rn(bnp[w][768 + o], 1e-5f)));
      me[j] = bnp[w][512 + o];
      be[j] = bnp[w][256 + o];
    }
#pragma unroll
    for (int r = 0; r < 4; ++r) {
      float* outp = Op[w] + (size_t)(m0 + row4 + r) * 256 + col0;
#pragma unroll
      for (int cq = 0; cq < CW / 4; ++cq) {
        float4 y;
        y.x = __fadd_rn(__fmul_rn(__fsub_rn(acc[w][r][cq*4+0], me[cq*4+0]), sc[cq*4+0]), be[cq*4+0]);
        y.y = __fadd_rn(__fmul_rn(__fsub_rn(acc[w][r][cq*4+1], me[cq*4+1]), sc[cq*4+1]), be[cq*4+1]);
        y.z = __fadd_rn(__fmul_rn(__fsub_rn(acc[w][r][cq*4+2], me[cq*4+2]), sc[cq*4+2]), be[cq*4+2]);
        y.w = __fadd_rn(__fmul_rn(__fsub_rn(acc[w][r][cq*4+3], me[cq*4+3]), sc[cq*4+3]), be[cq*4+3]);
        *(float4*)(outp + (cq << 2)) = y;
      }
    }
  }
}

// ---------------------------------------------------------------------------
// LIF over T (TAU=2, hard reset) + pack spikes into per-head 32-bit masks.
// ---------------------------------------------------------------------------
__global__ __launch_bounds__(256) void lif_pack3(
    const float* __restrict__ h0, const float* __restrict__ h1,
    const float* __restrict__ h2,
    u32* __restrict__ m0p, u32* __restrict__ m1p, u32* __restrict__ m2p)
{
  const float* h = (blockIdx.y == 0) ? h0 : (blockIdx.y == 1) ? h1 : h2;
  u32* mask      = (blockIdx.y == 0) ? m0p : (blockIdx.y == 1) ? m1p : m2p;
  const int blk = blockIdx.x;          // b*256 + n
  const int b = blk >> 8, n = blk & 255;
  const int c = threadIdx.x;
  const int wave = c >> 6, lane = c & 63;
  const size_t idx = ((size_t)b * 256 + n) * 256 + c;
  float v = 0.0f;
#pragma unroll
  for (int t = 0; t < 4; ++t) {
    float xv = h[idx + (size_t)t * BNC_];
    v = __fadd_rn(v, __fmul_rn(__fsub_rn(xv, v), 0.5f));
    bool s = (v >= 1.0f);
    u64 bal = __ballot(s);
    const int h0i = wave << 1;
    u32* mptr = mask + ((size_t)(t * 16 + b) * 8) * 256 + n;
    if (lane == 0)  mptr[(size_t)h0i * 256]       = (u32)bal;
    if (lane == 32) mptr[(size_t)(h0i + 1) * 256] = (u32)(bal >> 32);
    v = s ? 0.0f : v;
  }
}

// ---------------------------------------------------------------------------
// Fused attention: QK^T (popcount) + rel-bias + exact top-64 + sparse PV.
// (unchanged from round 4: 90 us, VALUBusy 83%)
// ---------------------------------------------------------------------------
__global__ __launch_bounds__(256) void attn_topk_pv(
    const u32* __restrict__ qmask, const u32* __restrict__ kmask,
    const u32* __restrict__ vmask, const float* __restrict__ table,
    float* __restrict__ outPV)
{
  __shared__ __align__(16) float bias[511];
  __shared__ __align__(16) u64 comp[4][2][132];  // [wave][half][entries]

  const int tbh = blockIdx.x;
  const int rg = blockIdx.y;
  const int hh = tbh & 7;
  const int tid = threadIdx.x;

  bias[tid] = table[tid * 8 + hh];
  if (tid < 255) bias[256 + tid] = table[(256 + tid) * 8 + hh];
  __syncthreads();

  const int wave = tid >> 6, lane = tid & 63;
  const int d = lane & 31, half = lane >> 5;

  // row-invariant per-lane K/V mask words (j = lane + 64r)
  u32 kmr[4], vmr[4];
#pragma unroll
  for (int r = 0; r < 4; ++r) {
    kmr[r] = kmask[((size_t)tbh << 8) + lane + (r << 6)];
    vmr[r] = vmask[((size_t)tbh << 8) + lane + (r << 6)];
  }
  const u64 below = (1ull << lane) - 1ull;
  u64* const clo = &comp[wave][0][0];
  u64* const chi = &comp[wave][1][0];

#pragma unroll 1
  for (int it = 0; it < 8; ++it) {
    const int i = (rg << 5) + (it << 2) + wave;
    const u32 qm = qmask[((size_t)tbh << 8) + i];
    float a[4]; u32 u[4];
#pragma unroll
    for (int r = 0; r < 4; ++r) {
      const int j = lane + (r << 6);
      const int m = __popc(qm & kmr[r]);
      float av = __fmul_rn((float)m, 0.0625f);     // * C^-0.5 = 1/16 exact
      av = __fadd_rn(av, bias[j - i + 255]);        // one rounded add == ref
      a[r] = av;
      const u32 bb = __float_as_uint(av);
      u[r] = bb ^ ((u32)((int)bb >> 31) | 0x80000000u);
    }
    // MSB-greedy exact 64th-largest; early exit when keep-set pinned
    u32 t = 0u;
    for (int bit = 31; bit >= 0; --bit) {
      const u32 cand = t | (1u << bit);
      const int cnt = __popcll(__ballot(u[0] >= cand)) +
                      __popcll(__ballot(u[1] >= cand)) +
                      __popcll(__ballot(u[2] >= cand)) +
                      __popcll(__ballot(u[3] >= cand));
      if (cnt >= 64) { t = cand; if (cnt == 64) break; }
    }
    // keep ballots -> compaction positions (j-ascending per half)
    const u64 B0 = __ballot(u[0] >= t), B1 = __ballot(u[1] >= t);
    const u64 B2 = __ballot(u[2] >= t), B3 = __ballot(u[3] >= t);
    const int c0 = __popcll(B0), c1 = __popcll(B1);
    const int c2 = __popcll(B2), c3 = __popcll(B3);
    const int p0 = __popcll(B0 & below);
    const int p1 = c0 + __popcll(B1 & below);
    const int p2 = __popcll(B2 & below);
    const int p3 = c2 + __popcll(B3 & below);
    if (u[0] >= t) clo[p0] = ((u64)vmr[0] << 32) | (u64)__float_as_uint(a[0]);
    if (u[1] >= t) clo[p1] = ((u64)vmr[1] << 32) | (u64)__float_as_uint(a[1]);
    if (u[2] >= t) chi[p2] = ((u64)vmr[2] << 32) | (u64)__float_as_uint(a[2]);
    if (u[3] >= t) chi[p3] = ((u64)vmr[3] << 32) | (u64)__float_as_uint(a[3]);
    const int nlo = c0 + c1, nhi = c2 + c3;
    if (lane < 2)      clo[nlo + lane] = 0ull;        // zero pads (odd tail)
    else if (lane < 4) chi[nhi + lane - 2] = 0ull;
    asm volatile("s_waitcnt lgkmcnt(0)" ::: "memory");

    // sparse PV: lane (half,d) walks its half's compact list, j-ascending
    const int n = half ? nhi : nlo;
    const u64* cp = half ? chi : clo;
    const int gn = (n + 1) >> 1;
    float s = 0.0f;
    for (int g = 0; g < gn; ++g) {
      uint4 e = *(const uint4*)(cp + ((size_t)g << 1));  // (a0,vm0,a1,vm1)
      const u32 mk0 = (u32)__builtin_amdgcn_sbfe((int)e.y, d, 1);
      s = __fadd_rn(s, __uint_as_float(e.x & mk0));
      const u32 mk1 = (u32)__builtin_amdgcn_sbfe((int)e.w, d, 1);
      s = __fadd_rn(s, __uint_as_float(e.z & mk1));
    }
    s += __shfl_xor(s, 32, 64);     // half0: s_lo + s_hi (ref order)
    if (half == 0)
      outPV[(((size_t)tbh << 8) + i) * 32 + d] = s;
  }
}

// ---------------------------------------------------------------------------
// attn_lif: LIF over T on PV output, [T,B,H,N,D] -> [T,B,N,C] transpose.
// ---------------------------------------------------------------------------
__global__ __launch_bounds__(256) void attn_lif(
    const float* __restrict__ pv, float* __restrict__ sout)
{
  const int blk = blockIdx.x;          // b*256 + n
  const int b = blk >> 8, n = blk & 255;
  const int c = threadIdx.x;
  const int hh = c >> 5, d = c & 31;
  float v = 0.0f;
#pragma unroll
  for (int t = 0; t < 4; ++t) {
    float xv = pv[(((size_t)(t * 16 + b) * 8 + hh) << 13) + (n << 5) + d];
    v = __fadd_rn(v, __fmul_rn(__fsub_rn(xv, v), 0.5f));
    bool s = (v >= 1.0f);
    sout[(((size_t)(t * 16 + b) << 8) + n) * 256 + c] = s ? 1.0f : 0.0f;
    v = s ? 0.0f : v;
  }
}

// ---------------------------------------------------------------------------
// Final LIF: hproj [T,B,N,C] -> d_out spikes [T,B,N,C]
// ---------------------------------------------------------------------------
__global__ __launch_bounds__(256) void final_lif(
    const float* __restrict__ hp, float* __restrict__ out)
{
  const size_t base = (size_t)blockIdx.x * 256 + threadIdx.x;
  float v = 0.0f;
#pragma unroll
  for (int t = 0; t < 4; ++t) {
    float xv = hp[base + (size_t)t * BNC_];
    v = __fadd_rn(v, __fmul_rn(__fsub_rn(xv, v), 0.5f));
    bool s = (v >= 1.0f);
    out[base + (size_t)t * BNC_] = s ? 1.0f : 0.0f;
    v = s ? 0.0f : v;
  }
}

// ---------------------------------------------------------------------------
extern "C" void kernel_launch(void* const* d_in, const int* in_sizes, int n_in,
                              void* d_out, int out_size, void* d_ws, size_t ws_size,
                              hipStream_t stream) {
  const float* x       = (const float*)d_in[0];
  const float* wq      = (const float*)d_in[1];
  const float* wk      = (const float*)d_in[2];
  const float* wv      = (const float*)d_in[3];
  const float* bnq     = (const float*)d_in[4];
  const float* bnk     = (const float*)d_in[5];
  const float* bnv     = (const float*)d_in[6];
  const float* proj_w  = (const float*)d_in[7];
  const float* proj_bn = (const float*)d_in[8];
  const float* rtable  = (const float*)d_in[9];
  float* out = (float*)d_out;

  float* ws = (float*)d_ws;
  float* hq = ws;                  // NELEM floats
  float* hk = ws + (size_t)NELEM;
  float* hv = ws + (size_t)NELEM * 2;
  u32* mq = (u32*)(ws + (size_t)NELEM * 3);   // 131072 u32 each
  u32* mk = mq + 131072;
  u32* mv = mk + 131072;
  float* outPV = hq;   // reuse: hq dead after mask extraction
  float* sout  = hk;
  float* hproj = hv;

  gemm_bn_l<3, 4><<<dim3(16, 64), 256, 0, stream>>>(
      x, wq, wk, wv, bnq, bnk, bnv, hq, hk, hv);

  lif_pack3<<<dim3(4096, 3), 256, 0, stream>>>(hq, hk, hv, mq, mk, mv);

  attn_topk_pv<<<dim3(512, 8), 256, 0, stream>>>(mq, mk, mv, rtable, outPV);

  attn_lif<<<4096, 256, 0, stream>>>(outPV, sout);

  gemm_bn_l<1, 8><<<dim3(8, 64), 256, 0, stream>>>(
      sout, proj_w, proj_w, proj_w, proj_bn, proj_bn, proj_bn,
      hproj, hproj, hproj);

  final_lif<<<4096, 256, 0, stream>>>(hproj, out);
}